// Round 4
// baseline (1234.687 us; speedup 1.0000x reference)
//
#include <hip/hip_runtime.h>

#define BB 64
#define TT 1024
#define HH 1024
#define NN 64

// ---------------------------------------------------------------------------
// Kernel 1: emission = text_vec @ W_em^T + b_em   (fp32 vector GEMM)
// 512 blocks x 256 threads; block tile 128 rows x 64 cols; thread tile 8x4.
// ---------------------------------------------------------------------------
__global__ __launch_bounds__(256) void emission_gemm(
    const float* __restrict__ A, const float* __restrict__ W,
    const float* __restrict__ bias, float* __restrict__ out)
{
    __shared__ __align__(16) float At[64][132];   // 33.8 KB
    __shared__ __align__(16) float Wt[64][NN];    // 16 KB

    const int t  = threadIdx.x;
    const int cg = t & 15, rg = t >> 4;
    const int r0 = blockIdx.x * 128 + rg * 8;
    const int c0 = cg * 4;

    const int arow = t >> 1;
    const int ak   = (t & 1) * 32;
    const float* Aptr = A + (size_t)(blockIdx.x * 128 + arow) * HH + ak;
    const int stc = t & 63, stq = t >> 6;
    const float* Wptr = W + (size_t)stc * HH + stq * 16;

    float4 av[8], wv[4];
#pragma unroll
    for (int u = 0; u < 8; ++u) av[u] = *(const float4*)(Aptr + 4 * u);
#pragma unroll
    for (int u = 0; u < 4; ++u) wv[u] = *(const float4*)(Wptr + 4 * u);

    float acc[8][4];
#pragma unroll
    for (int r = 0; r < 8; ++r)
#pragma unroll
        for (int c = 0; c < 4; ++c) acc[r][c] = 0.0f;

    for (int kt = 0; kt < HH; kt += 64) {
        __syncthreads();   // previous tile fully consumed
#pragma unroll
        for (int u = 0; u < 8; ++u) {
            At[ak + 4 * u + 0][arow] = av[u].x;
            At[ak + 4 * u + 1][arow] = av[u].y;
            At[ak + 4 * u + 2][arow] = av[u].z;
            At[ak + 4 * u + 3][arow] = av[u].w;
        }
#pragma unroll
        for (int u = 0; u < 4; ++u) {
            Wt[stq * 16 + 4 * u + 0][stc] = wv[u].x;
            Wt[stq * 16 + 4 * u + 1][stc] = wv[u].y;
            Wt[stq * 16 + 4 * u + 2][stc] = wv[u].z;
            Wt[stq * 16 + 4 * u + 3][stc] = wv[u].w;
        }
        __syncthreads();

        if (kt + 64 < HH) {   // prefetch next tile; latency hides under compute
#pragma unroll
            for (int u = 0; u < 8; ++u)
                av[u] = *(const float4*)(Aptr + (kt + 64) + 4 * u);
#pragma unroll
            for (int u = 0; u < 4; ++u)
                wv[u] = *(const float4*)(Wptr + (kt + 64) + 4 * u);
        }

#pragma unroll 8
        for (int kk = 0; kk < 64; ++kk) {
            const float4 a0 = *(const float4*)&At[kk][rg * 8];
            const float4 a1 = *(const float4*)&At[kk][rg * 8 + 4];
            const float4 w  = *(const float4*)&Wt[kk][c0];
            acc[0][0] += a0.x * w.x; acc[0][1] += a0.x * w.y; acc[0][2] += a0.x * w.z; acc[0][3] += a0.x * w.w;
            acc[1][0] += a0.y * w.x; acc[1][1] += a0.y * w.y; acc[1][2] += a0.y * w.z; acc[1][3] += a0.y * w.w;
            acc[2][0] += a0.z * w.x; acc[2][1] += a0.z * w.y; acc[2][2] += a0.z * w.z; acc[2][3] += a0.z * w.w;
            acc[3][0] += a0.w * w.x; acc[3][1] += a0.w * w.y; acc[3][2] += a0.w * w.z; acc[3][3] += a0.w * w.w;
            acc[4][0] += a1.x * w.x; acc[4][1] += a1.x * w.y; acc[4][2] += a1.x * w.z; acc[4][3] += a1.x * w.w;
            acc[5][0] += a1.y * w.x; acc[5][1] += a1.y * w.y; acc[5][2] += a1.y * w.z; acc[5][3] += a1.y * w.w;
            acc[6][0] += a1.z * w.x; acc[6][1] += a1.z * w.y; acc[6][2] += a1.z * w.z; acc[6][3] += a1.z * w.w;
            acc[7][0] += a1.w * w.x; acc[7][1] += a1.w * w.y; acc[7][2] += a1.w * w.z; acc[7][3] += a1.w * w.w;
        }
    }

    const float4 b4 = *(const float4*)&bias[c0];
#pragma unroll
    for (int r = 0; r < 8; ++r) {
        float4 o;
        o.x = acc[r][0] + b4.x;
        o.y = acc[r][1] + b4.y;
        o.z = acc[r][2] + b4.z;
        o.w = acc[r][3] + b4.w;
        *(float4*)&out[(size_t)(r0 + r) * NN + c0] = o;
    }
}

// ---------------------------------------------------------------------------
// Kernel 2: Viterbi forward, values only. ONE WAVE (64 lanes) per batch.
//
// ROUND-3 DIAGNOSIS: two different operand stores (scratch r2 / LDS r3) gave
// identical ~960 cyc/step -> the bottleneck is per-group operand-load latency
// exposed on the serial chain (compiler sinks each group's ds_reads to right
// before their consuming adds; 8 groups x ~80 cyc exposed = the gap).
//
// FIX: issue ALL 16 ds_read_b128 (trans as float4 columns) at iteration top:
//   - opaque zero offset (asm "+v") makes addresses loop-variant -> LICM
//     cannot hoist them out of the loop (round-2 spill disaster) and they
//     cannot be rematerialized elsewhere;
//   - sched_barrier(0) after the load block -> loads cannot sink into the
//     consume chain (round-3 pathology). lgkmcnt waits are counted by the
//     compiler; the ~120 cyc LDS latency hides under the 128-cyc readlane
//     issue phase (readlanes have no LDS dependence).
// __launch_bounds__(64,1): w[16] float4 = 64 VGPR iteration-local live set.
// Exactness: fp max associative/commutative (no NaNs); add monotone so
// max_i(x_i)+e == max_i(x_i+e) bit-exactly.
// ---------------------------------------------------------------------------
__device__ __forceinline__ float max3f(float a, float b, float c) {
    float d;
    asm("v_max3_f32 %0, %1, %2, %3" : "=v"(d) : "v"(a), "v"(b), "v"(c));
    return d;
}

__global__ __launch_bounds__(64, 1) void viterbi_forward(
    const float* __restrict__ emission,
    const float* __restrict__ start_trans,
    const float* __restrict__ end_trans,
    const float* __restrict__ trans,
    float* __restrict__ scores,          // [B, T, N]
    int* __restrict__ last_arr)          // [B]
{
    __shared__ __align__(16) float4 tcp4[16][NN];  // 16 KB: tcp4[q][j] = trans[4q..4q+3][j]
    __shared__ float fs[NN];

    const int b = blockIdx.x;
    const int j = threadIdx.x;           // 0..63, one full wave

    // stage trans as float4 columns (coalesced global reads, b128 LDS writes)
#pragma unroll
    for (int q = 0; q < 16; ++q) {
        float4 w;
        w.x = trans[(4 * q + 0) * NN + j];
        w.y = trans[(4 * q + 1) * NN + j];
        w.z = trans[(4 * q + 2) * NN + j];
        w.w = trans[(4 * q + 3) * NN + j];
        tcp4[q][j] = w;
    }
    __syncthreads();                     // single-wave block: cheap

    const float* eb = emission + (size_t)b * TT * NN;
    float* sb = scores + (size_t)b * TT * NN;

    float cur = start_trans[j] + eb[j];
    sb[j] = cur;

    // 3-deep emission prefetch: slack ~3 steps > HBM-miss latency
    float eA = eb[(size_t)1 * NN + j];
    float eB = eb[(size_t)2 * NN + j];
    float eC = eb[(size_t)3 * NN + j];

    for (int t = 1; t < TT; ++t) {
        const float e = eA;
        eA = eB;
        eB = eC;
        const int tn = (t + 3 < TT) ? (t + 3) : (TT - 1);
        eC = eb[(size_t)tn * NN + j];    // consumed 3 iterations later

        // ---- operand phase: all 16 ds_read_b128 issued here, pinned ----
        int off = 0;
        asm("" : "+v"(off));             // opaque 0: defeats LICM/remat
        float4 w[16];
#pragma unroll
        for (int q = 0; q < 16; ++q) w[q] = tcp4[q][j + off];
        __builtin_amdgcn_sched_barrier(0);   // loads cannot sink past here

        // ---- compute phase: readlane gather + add + max3 tree ----
        const int ic = __float_as_int(cur);
        float part[8];
#pragma unroll
        for (int g = 0; g < 8; ++g) {
            const float4 wa = w[2 * g];
            const float4 wb = w[2 * g + 1];
            const float v0 = __int_as_float(__builtin_amdgcn_readlane(ic, 8 * g + 0)) + wa.x;
            const float v1 = __int_as_float(__builtin_amdgcn_readlane(ic, 8 * g + 1)) + wa.y;
            const float v2 = __int_as_float(__builtin_amdgcn_readlane(ic, 8 * g + 2)) + wa.z;
            const float v3 = __int_as_float(__builtin_amdgcn_readlane(ic, 8 * g + 3)) + wa.w;
            const float v4 = __int_as_float(__builtin_amdgcn_readlane(ic, 8 * g + 4)) + wb.x;
            const float v5 = __int_as_float(__builtin_amdgcn_readlane(ic, 8 * g + 5)) + wb.y;
            const float v6 = __int_as_float(__builtin_amdgcn_readlane(ic, 8 * g + 6)) + wb.z;
            const float v7 = __int_as_float(__builtin_amdgcn_readlane(ic, 8 * g + 7)) + wb.w;
            part[g] = max3f(max3f(v0, v1, v2),
                            max3f(v3, v4, v5),
                            fmaxf(v6, v7));
        }
        const float m = max3f(max3f(part[0], part[1], part[2]),
                              max3f(part[3], part[4], part[5]),
                              fmaxf(part[6], part[7]));

        cur = m + e;
        sb[(size_t)t * NN + j] = cur;    // off-chain store
    }

    fs[j] = cur + end_trans[j];
    __syncthreads();                     // single-wave block: near-free
    if (j == 0) {
        float best = fs[0];
        int tag = 0;
#pragma unroll
        for (int i = 1; i < NN; ++i)
            if (fs[i] > best) { best = fs[i]; tag = i; }   // first-index ties
        last_arr[b] = tag;
    }
}

// ---------------------------------------------------------------------------
// Kernel 3: hist[t-1][j] = argmax_i(scores[t-1][i] + trans[i][j]) in parallel.
// Left-wins-ties adjacent merge tree == numpy first-index argmax.
// ---------------------------------------------------------------------------
__global__ __launch_bounds__(256) void viterbi_hist(
    const float* __restrict__ scores,
    const float* __restrict__ trans,
    unsigned char* __restrict__ hist)    // [B, T-1, N]
{
    __shared__ __align__(16) float sp[64][NN];

    const int b   = blockIdx.y;
    const int g   = blockIdx.x;
    const int j   = threadIdx.x & 63;
    const int sub = threadIdx.x >> 6;

    float tc[NN];
#pragma unroll
    for (int i = 0; i < NN; ++i) tc[i] = trans[i * NN + j];

    const float* base = scores + (size_t)b * TT * NN + (size_t)g * 64 * NN;
    float4* spv = (float4*)&sp[0][0];
    for (int idx = threadIdx.x; idx < 64 * NN / 4; idx += 256)
        spv[idx] = ((const float4*)base)[idx];
    __syncthreads();

    for (int m = 0; m < 16; ++m) {
        const int tl = sub * 16 + m;
        const int pp = g * 64 + tl;      // pp = t-1
        if (pp > TT - 2) continue;

        const float* row = &sp[tl][0];
        float av[32];
        int   ai[32];
#pragma unroll
        for (int q = 0; q < 16; ++q) {
            const float4 s = ((const float4*)row)[q];
            const float x0 = s.x + tc[4 * q + 0];
            const float x1 = s.y + tc[4 * q + 1];
            const bool g0 = x0 >= x1;
            av[2 * q]     = g0 ? x0 : x1;
            ai[2 * q]     = g0 ? 4 * q + 0 : 4 * q + 1;
            const float x2 = s.z + tc[4 * q + 2];
            const float x3 = s.w + tc[4 * q + 3];
            const bool g1 = x2 >= x3;
            av[2 * q + 1] = g1 ? x2 : x3;
            ai[2 * q + 1] = g1 ? 4 * q + 2 : 4 * q + 3;
        }
#pragma unroll
        for (int k = 0; k < 16; ++k) {
            const bool ge = av[2 * k] >= av[2 * k + 1];
            av[k] = ge ? av[2 * k] : av[2 * k + 1];
            ai[k] = ge ? ai[2 * k] : ai[2 * k + 1];
        }
#pragma unroll
        for (int k = 0; k < 8; ++k) {
            const bool ge = av[2 * k] >= av[2 * k + 1];
            av[k] = ge ? av[2 * k] : av[2 * k + 1];
            ai[k] = ge ? ai[2 * k] : ai[2 * k + 1];
        }
#pragma unroll
        for (int k = 0; k < 4; ++k) {
            const bool ge = av[2 * k] >= av[2 * k + 1];
            av[k] = ge ? av[2 * k] : av[2 * k + 1];
            ai[k] = ge ? ai[2 * k] : ai[2 * k + 1];
        }
#pragma unroll
        for (int k = 0; k < 2; ++k) {
            const bool ge = av[2 * k] >= av[2 * k + 1];
            av[k] = ge ? av[2 * k] : av[2 * k + 1];
            ai[k] = ge ? ai[2 * k] : ai[2 * k + 1];
        }
        const bool ge = av[0] >= av[1];
        const int best = ge ? ai[0] : ai[1];

        hist[((size_t)b * (TT - 1) + pp) * NN + j] = (unsigned char)best;
    }
}

// ---------------------------------------------------------------------------
// Kernel 4: segmented-speculative backtrack. 16 segments x 64 candidate tags
// = 1024 threads; each walks its 64-step segment (dependent L2-hot byte
// reads) to build the segment's tag->tag map; thread 0 stitches the 16 maps;
// 16 walkers re-walk with the true entry tags and emit the path.
// ---------------------------------------------------------------------------
__global__ __launch_bounds__(1024) void viterbi_backtrack(
    const unsigned char* __restrict__ hist,   // [B, T-1, N]
    const int* __restrict__ last_arr,
    float* __restrict__ pred)
{
    __shared__ unsigned char mmap[16][64];
    __shared__ unsigned char in_tag[16];
    __shared__ unsigned char tagbuf[TT];

    const int b   = blockIdx.x;
    const int tid = threadIdx.x;
    const unsigned char* hb = hist + (size_t)b * (TT - 1) * NN;

    // phase 1: speculative segment maps
    const int s  = tid >> 6;
    const int x  = tid & 63;
    const int hi = (s == 15) ? (TT - 1) : (s * 64 + 63);
    const int lo = (s == 0) ? 1 : (s * 64);
    int cur = x;
    for (int t = hi; t >= lo; --t) cur = hb[(size_t)(t - 1) * NN + cur];
    mmap[s][x] = (unsigned char)cur;
    __syncthreads();

    // phase 2: stitch maps serially (16 steps)
    if (tid == 0) {
        int tag = last_arr[b];
        tagbuf[TT - 1] = (unsigned char)tag;
        for (int s2 = 15; s2 >= 0; --s2) {
            in_tag[s2] = (unsigned char)tag;   // tag at position hi_s
            tag = mmap[s2][tag];
        }
    }
    __syncthreads();

    // phase 3: 16 true re-walks in parallel; seg s writes positions
    // [lo-1, hi-1] (disjoint union = 0..1022)
    if (tid < 16) {
        const int s3  = tid;
        const int hi3 = (s3 == 15) ? (TT - 1) : (s3 * 64 + 63);
        const int lo3 = (s3 == 0) ? 1 : (s3 * 64);
        int c3 = in_tag[s3];
        for (int t = hi3; t >= lo3; --t) {
            c3 = hb[(size_t)(t - 1) * NN + c3];
            tagbuf[t - 1] = (unsigned char)c3;
        }
    }
    __syncthreads();

    float* pb = pred + (size_t)b * TT;
    for (int i = tid; i < TT; i += 1024) pb[i] = (float)tagbuf[i];
}

// ---------------------------------------------------------------------------
// Launch
// ---------------------------------------------------------------------------
extern "C" void kernel_launch(void* const* d_in, const int* in_sizes, int n_in,
                              void* d_out, int out_size, void* d_ws, size_t ws_size,
                              hipStream_t stream)
{
    const float* text_vec    = (const float*)d_in[0];
    // d_in[1] = mask (all true for this problem; unused)
    const float* W_em        = (const float*)d_in[2];
    const float* b_em        = (const float*)d_in[3];
    const float* start_trans = (const float*)d_in[4];
    const float* end_trans   = (const float*)d_in[5];
    const float* trans       = (const float*)d_in[6];

    float* emission = (float*)d_out;                        // [B*T*N]
    float* pred     = (float*)d_out + (size_t)BB * TT * NN; // [B*T]

    float* scores       = (float*)d_ws;                                    // 16.78 MB
    unsigned char* hist = (unsigned char*)d_ws + (size_t)BB * TT * NN * 4; // 4.19 MB
    int* last_arr       = (int*)(hist + (size_t)BB * (TT - 1) * NN);       // 256 B

    emission_gemm<<<dim3(512), dim3(256), 0, stream>>>(text_vec, W_em, b_em, emission);
    viterbi_forward<<<dim3(BB), dim3(64), 0, stream>>>(emission, start_trans, end_trans,
                                                       trans, scores, last_arr);
    viterbi_hist<<<dim3(16, BB), dim3(256), 0, stream>>>(scores, trans, hist);
    viterbi_backtrack<<<dim3(BB), dim3(1024), 0, stream>>>(hist, last_arr, pred);
}

// Round 5
// 980.542 us; speedup vs baseline: 1.2592x; 1.2592x over previous
//
#include <hip/hip_runtime.h>

#define BB 64
#define TT 1024
#define HH 1024
#define NN 64

// ---------------------------------------------------------------------------
// Kernel 1: emission = text_vec @ W_em^T + b_em   (fp32 vector GEMM)
// 512 blocks x 256 threads; block tile 128 rows x 64 cols; thread tile 8x4.
// ---------------------------------------------------------------------------
__global__ __launch_bounds__(256) void emission_gemm(
    const float* __restrict__ A, const float* __restrict__ W,
    const float* __restrict__ bias, float* __restrict__ out)
{
    __shared__ __align__(16) float At[64][132];   // 33.8 KB
    __shared__ __align__(16) float Wt[64][NN];    // 16 KB

    const int t  = threadIdx.x;
    const int cg = t & 15, rg = t >> 4;
    const int r0 = blockIdx.x * 128 + rg * 8;
    const int c0 = cg * 4;

    const int arow = t >> 1;
    const int ak   = (t & 1) * 32;
    const float* Aptr = A + (size_t)(blockIdx.x * 128 + arow) * HH + ak;
    const int stc = t & 63, stq = t >> 6;
    const float* Wptr = W + (size_t)stc * HH + stq * 16;

    float4 av[8], wv[4];
#pragma unroll
    for (int u = 0; u < 8; ++u) av[u] = *(const float4*)(Aptr + 4 * u);
#pragma unroll
    for (int u = 0; u < 4; ++u) wv[u] = *(const float4*)(Wptr + 4 * u);

    float acc[8][4];
#pragma unroll
    for (int r = 0; r < 8; ++r)
#pragma unroll
        for (int c = 0; c < 4; ++c) acc[r][c] = 0.0f;

    for (int kt = 0; kt < HH; kt += 64) {
        __syncthreads();   // previous tile fully consumed
#pragma unroll
        for (int u = 0; u < 8; ++u) {
            At[ak + 4 * u + 0][arow] = av[u].x;
            At[ak + 4 * u + 1][arow] = av[u].y;
            At[ak + 4 * u + 2][arow] = av[u].z;
            At[ak + 4 * u + 3][arow] = av[u].w;
        }
#pragma unroll
        for (int u = 0; u < 4; ++u) {
            Wt[stq * 16 + 4 * u + 0][stc] = wv[u].x;
            Wt[stq * 16 + 4 * u + 1][stc] = wv[u].y;
            Wt[stq * 16 + 4 * u + 2][stc] = wv[u].z;
            Wt[stq * 16 + 4 * u + 3][stc] = wv[u].w;
        }
        __syncthreads();

        if (kt + 64 < HH) {   // prefetch next tile; latency hides under compute
#pragma unroll
            for (int u = 0; u < 8; ++u)
                av[u] = *(const float4*)(Aptr + (kt + 64) + 4 * u);
#pragma unroll
            for (int u = 0; u < 4; ++u)
                wv[u] = *(const float4*)(Wptr + (kt + 64) + 4 * u);
        }

#pragma unroll 8
        for (int kk = 0; kk < 64; ++kk) {
            const float4 a0 = *(const float4*)&At[kk][rg * 8];
            const float4 a1 = *(const float4*)&At[kk][rg * 8 + 4];
            const float4 w  = *(const float4*)&Wt[kk][c0];
            acc[0][0] += a0.x * w.x; acc[0][1] += a0.x * w.y; acc[0][2] += a0.x * w.z; acc[0][3] += a0.x * w.w;
            acc[1][0] += a0.y * w.x; acc[1][1] += a0.y * w.y; acc[1][2] += a0.y * w.z; acc[1][3] += a0.y * w.w;
            acc[2][0] += a0.z * w.x; acc[2][1] += a0.z * w.y; acc[2][2] += a0.z * w.z; acc[2][3] += a0.z * w.w;
            acc[3][0] += a0.w * w.x; acc[3][1] += a0.w * w.y; acc[3][2] += a0.w * w.z; acc[3][3] += a0.w * w.w;
            acc[4][0] += a1.x * w.x; acc[4][1] += a1.x * w.y; acc[4][2] += a1.x * w.z; acc[4][3] += a1.x * w.w;
            acc[5][0] += a1.y * w.x; acc[5][1] += a1.y * w.y; acc[5][2] += a1.y * w.z; acc[5][3] += a1.y * w.w;
            acc[6][0] += a1.z * w.x; acc[6][1] += a1.z * w.y; acc[6][2] += a1.z * w.z; acc[6][3] += a1.z * w.w;
            acc[7][0] += a1.w * w.x; acc[7][1] += a1.w * w.y; acc[7][2] += a1.w * w.z; acc[7][3] += a1.w * w.w;
        }
    }

    const float4 b4 = *(const float4*)&bias[c0];
#pragma unroll
    for (int r = 0; r < 8; ++r) {
        float4 o;
        o.x = acc[r][0] + b4.x;
        o.y = acc[r][1] + b4.y;
        o.z = acc[r][2] + b4.z;
        o.w = acc[r][3] + b4.w;
        *(float4*)&out[(size_t)(r0 + r) * NN + c0] = o;
    }
}

// ---------------------------------------------------------------------------
// Kernel 2: Viterbi forward — FULL INLINE-ASM LOOP, one wave per batch.
//
// ROUNDS 1-4 LESSON: at HIP source level the scheduler/allocator pair always
// re-serializes or spills the 64-value trans column (its pressure heuristic
// caps ~68 VGPRs regardless of launch_bounds). Escape hatch: one asm block
// with hard-coded physical registers (clobbers cannot be spilled/sunk/CSE'd).
//
//   v64-v127 : trans[i][j] for i=0..63, loaded ONCE from global (L2-hot)
//   v40-v44  : emission prefetch queue e(t..t+4), shift-by-2 per pair
//   v45/v46  : cur ping-pong (step parity), stores issue directly from them
//   s8-s23   : two readlane banks (ping-pong per 8-lane group)
//   per step : 64 v_readlane + 64 v_add(sgpr,vgpr) + 40 max3/max ~= 336 cyc
//   waits    : vmcnt(3) before each cur update (WAR insurance on v45/v46),
//              vmcnt(2) before e-queue shift (forces 1-pair-old loads)
//   loop     : 511 pairs (t=1..1022) + tail step (t=1023)
//
// Exactness: identical arithmetic to all prior versions (fp max exactly
// associative/commutative, no NaNs; add monotone).
// ---------------------------------------------------------------------------
#define VRL(S,VC,L)  "v_readlane_b32 s" #S ", " VC ", " #L "\n\t"
#define VADD(D,S,T)  "v_add_f32 v" #D ", s" #S ", v" #T "\n\t"
#define RLG(VC,S0,S1,S2,S3,S4,S5,S6,S7,L0,L1,L2,L3,L4,L5,L6,L7) \
  VRL(S0,VC,L0) VRL(S1,VC,L1) VRL(S2,VC,L2) VRL(S3,VC,L3) \
  VRL(S4,VC,L4) VRL(S5,VC,L5) VRL(S6,VC,L6) VRL(S7,VC,L7)
#define ADDG(S0,S1,S2,S3,S4,S5,S6,S7,T0,T1,T2,T3,T4,T5,T6,T7) \
  VADD(48,S0,T0) VADD(49,S1,T1) VADD(50,S2,T2) VADD(51,S3,T3) \
  VADD(52,S4,T4) VADD(53,S5,T5) VADD(54,S6,T6) VADD(55,S7,T7)
#define MAXF \
  "v_max3_f32 v56, v48, v49, v50\n\t" \
  "v_max3_f32 v57, v51, v52, v53\n\t" \
  "v_max_f32 v58, v54, v55\n\t" \
  "v_max3_f32 v59, v56, v57, v58\n\t"
#define MAXN \
  "v_max3_f32 v56, v48, v49, v50\n\t" \
  "v_max3_f32 v57, v51, v52, v53\n\t" \
  "v_max_f32 v58, v54, v55\n\t" \
  "v_max3_f32 v60, v56, v57, v58\n\t" \
  "v_max_f32 v59, v59, v60\n\t"
// one full 64-way gather+add+max into v59 (macc); VC = cur register string
#define STEP_CORE(VC) \
  RLG(VC, 8,9,10,11,12,13,14,15, 0,1,2,3,4,5,6,7) \
  ADDG(8,9,10,11,12,13,14,15, 64,65,66,67,68,69,70,71) \
  RLG(VC, 16,17,18,19,20,21,22,23, 8,9,10,11,12,13,14,15) \
  MAXF \
  ADDG(16,17,18,19,20,21,22,23, 72,73,74,75,76,77,78,79) \
  RLG(VC, 8,9,10,11,12,13,14,15, 16,17,18,19,20,21,22,23) \
  MAXN \
  ADDG(8,9,10,11,12,13,14,15, 80,81,82,83,84,85,86,87) \
  RLG(VC, 16,17,18,19,20,21,22,23, 24,25,26,27,28,29,30,31) \
  MAXN \
  ADDG(16,17,18,19,20,21,22,23, 88,89,90,91,92,93,94,95) \
  RLG(VC, 8,9,10,11,12,13,14,15, 32,33,34,35,36,37,38,39) \
  MAXN \
  ADDG(8,9,10,11,12,13,14,15, 96,97,98,99,100,101,102,103) \
  RLG(VC, 16,17,18,19,20,21,22,23, 40,41,42,43,44,45,46,47) \
  MAXN \
  ADDG(16,17,18,19,20,21,22,23, 104,105,106,107,108,109,110,111) \
  RLG(VC, 8,9,10,11,12,13,14,15, 48,49,50,51,52,53,54,55) \
  MAXN \
  ADDG(8,9,10,11,12,13,14,15, 112,113,114,115,116,117,118,119) \
  RLG(VC, 16,17,18,19,20,21,22,23, 56,57,58,59,60,61,62,63) \
  MAXN \
  ADDG(16,17,18,19,20,21,22,23, 120,121,122,123,124,125,126,127) \
  MAXN
#define VTL(D,OFF) "global_load_dword v" #D ", v33, %[tb] offset:" #OFF "\n\t"
#define TWIN16(A,B,C,D,E,F,G,H,I,J,K,L,M,N,O,P) \
  VTL(A,0) VTL(B,256) VTL(C,512) VTL(D,768) VTL(E,1024) VTL(F,1280) \
  VTL(G,1536) VTL(H,1792) VTL(I,2048) VTL(J,2304) VTL(K,2560) VTL(L,2816) \
  VTL(M,3072) VTL(N,3328) VTL(O,3584) VTL(P,3840)

__global__ __launch_bounds__(64) void viterbi_forward(
    const float* __restrict__ emission,
    const float* __restrict__ start_trans,
    const float* __restrict__ end_trans,
    const float* __restrict__ trans,
    float* __restrict__ scores,          // [B, T, N]
    int* __restrict__ last_arr)          // [B]
{
    __shared__ float fs[NN];

    const int b = blockIdx.x;
    const int j = threadIdx.x;           // 0..63, one full wave
    const float st = start_trans[j];
    const unsigned long long tb  = (unsigned long long)(uintptr_t)trans;
    const unsigned long long ebp = (unsigned long long)(uintptr_t)(emission + (size_t)b * TT * NN);
    const unsigned long long sbp = (unsigned long long)(uintptr_t)(scores   + (size_t)b * TT * NN);
    const int tv = j * 4;
    float curout;

    asm volatile(
        // ---- prologue: T[i][j] -> v(64+i), 4 windows of 16 loads ----
        "s_mov_b32 s24, 511\n\t"
        "v_mov_b32 v33, %[tv]\n\t"
        TWIN16(64,65,66,67,68,69,70,71,72,73,74,75,76,77,78,79)
        "v_add_u32 v33, 0x1000, v33\n\t"
        TWIN16(80,81,82,83,84,85,86,87,88,89,90,91,92,93,94,95)
        "v_add_u32 v33, 0x1000, v33\n\t"
        TWIN16(96,97,98,99,100,101,102,103,104,105,106,107,108,109,110,111)
        "v_add_u32 v33, 0x1000, v33\n\t"
        TWIN16(112,113,114,115,116,117,118,119,120,121,122,123,124,125,126,127)
        // ---- e prologue: e0 -> v39, e(1..5) -> v40..v44 ----
        "global_load_dword v39, %[tv], %[eb]\n\t"
        "global_load_dword v40, %[tv], %[eb] offset:256\n\t"
        "global_load_dword v41, %[tv], %[eb] offset:512\n\t"
        "global_load_dword v42, %[tv], %[eb] offset:768\n\t"
        "global_load_dword v43, %[tv], %[eb] offset:1024\n\t"
        "global_load_dword v44, %[tv], %[eb] offset:1280\n\t"
        "s_waitcnt vmcnt(5)\n\t"                 // T + e0 complete
        "v_add_f32 v45, %[st], v39\n\t"          // cur(0)
        "v_mov_b32 v35, %[tv]\n\t"
        "global_store_dword v35, v45, %[sb]\n\t" // scores row 0
        "v_add_u32 v35, 0x100, v35\n\t"          // store offset -> row 1
        "v_add_u32 v34, 0x600, %[tv]\n\t"        // e-load offset -> row 6
        // ---- main loop: 511 pairs, steps (2k+1, 2k+2) ----
        "Lpair_%=:\n\t"
        // step A: reads v45, writes v46, e = v40
        STEP_CORE("v45")
        "s_waitcnt vmcnt(3)\n\t"
        "v_add_f32 v46, v59, v40\n\t"
        "global_store_dword v35, v46, %[sb]\n\t"
        // step B: reads v46, writes v45, e = v41
        STEP_CORE("v46")
        "s_waitcnt vmcnt(3)\n\t"
        "v_add_f32 v45, v59, v41\n\t"
        "global_store_dword v35, v45, %[sb] offset:256\n\t"
        "v_add_u32 v35, 0x200, v35\n\t"
        // e-queue shift by 2 + refill
        "s_waitcnt vmcnt(2)\n\t"                 // prev pair's loads done
        "v_mov_b32 v40, v42\n\t"
        "v_mov_b32 v41, v43\n\t"
        "v_mov_b32 v42, v44\n\t"
        "global_load_dword v43, v34, %[eb]\n\t"
        "global_load_dword v44, v34, %[eb] offset:256\n\t"
        "v_add_u32 v34, 0x200, v34\n\t"
        "s_sub_u32 s24, s24, 1\n\t"
        "s_cmp_lg_u32 s24, 0\n\t"
        "s_cbranch_scc1 Lpair_%=\n\t"
        // ---- tail: step t=1023, reads v45, writes v46, e = v40 ----
        STEP_CORE("v45")
        "s_waitcnt vmcnt(3)\n\t"
        "v_add_f32 v46, v59, v40\n\t"
        "global_store_dword v35, v46, %[sb]\n\t"
        "s_waitcnt vmcnt(0)\n\t"
        "v_mov_b32 %[cout], v46\n\t"
        : [cout] "=v"(curout)
        : [tv] "v"(tv), [st] "v"(st), [tb] "s"(tb), [eb] "s"(ebp), [sb] "s"(sbp)
        : "memory",
          "s8","s9","s10","s11","s12","s13","s14","s15",
          "s16","s17","s18","s19","s20","s21","s22","s23","s24",
          "v33","v34","v35","v36","v37","v38","v39","v40","v41","v42","v43",
          "v44","v45","v46","v47","v48","v49","v50","v51","v52","v53","v54",
          "v55","v56","v57","v58","v59","v60",
          "v64","v65","v66","v67","v68","v69","v70","v71",
          "v72","v73","v74","v75","v76","v77","v78","v79",
          "v80","v81","v82","v83","v84","v85","v86","v87",
          "v88","v89","v90","v91","v92","v93","v94","v95",
          "v96","v97","v98","v99","v100","v101","v102","v103",
          "v104","v105","v106","v107","v108","v109","v110","v111",
          "v112","v113","v114","v115","v116","v117","v118","v119",
          "v120","v121","v122","v123","v124","v125","v126","v127");

    fs[j] = curout + end_trans[j];
    __syncthreads();                     // single-wave block: near-free
    if (j == 0) {
        float best = fs[0];
        int tag = 0;
#pragma unroll
        for (int i = 1; i < NN; ++i)
            if (fs[i] > best) { best = fs[i]; tag = i; }   // first-index ties
        last_arr[b] = tag;
    }
}

// ---------------------------------------------------------------------------
// Kernel 3: hist[t-1][j] = argmax_i(scores[t-1][i] + trans[i][j]) in parallel.
// Left-wins-ties adjacent merge tree == numpy first-index argmax.
// ---------------------------------------------------------------------------
__global__ __launch_bounds__(256) void viterbi_hist(
    const float* __restrict__ scores,
    const float* __restrict__ trans,
    unsigned char* __restrict__ hist)    // [B, T-1, N]
{
    __shared__ __align__(16) float sp[64][NN];

    const int b   = blockIdx.y;
    const int g   = blockIdx.x;
    const int j   = threadIdx.x & 63;
    const int sub = threadIdx.x >> 6;

    float tc[NN];
#pragma unroll
    for (int i = 0; i < NN; ++i) tc[i] = trans[i * NN + j];

    const float* base = scores + (size_t)b * TT * NN + (size_t)g * 64 * NN;
    float4* spv = (float4*)&sp[0][0];
    for (int idx = threadIdx.x; idx < 64 * NN / 4; idx += 256)
        spv[idx] = ((const float4*)base)[idx];
    __syncthreads();

    for (int m = 0; m < 16; ++m) {
        const int tl = sub * 16 + m;
        const int pp = g * 64 + tl;      // pp = t-1
        if (pp > TT - 2) continue;

        const float* row = &sp[tl][0];
        float av[32];
        int   ai[32];
#pragma unroll
        for (int q = 0; q < 16; ++q) {
            const float4 s = ((const float4*)row)[q];
            const float x0 = s.x + tc[4 * q + 0];
            const float x1 = s.y + tc[4 * q + 1];
            const bool g0 = x0 >= x1;
            av[2 * q]     = g0 ? x0 : x1;
            ai[2 * q]     = g0 ? 4 * q + 0 : 4 * q + 1;
            const float x2 = s.z + tc[4 * q + 2];
            const float x3 = s.w + tc[4 * q + 3];
            const bool g1 = x2 >= x3;
            av[2 * q + 1] = g1 ? x2 : x3;
            ai[2 * q + 1] = g1 ? 4 * q + 2 : 4 * q + 3;
        }
#pragma unroll
        for (int k = 0; k < 16; ++k) {
            const bool ge = av[2 * k] >= av[2 * k + 1];
            av[k] = ge ? av[2 * k] : av[2 * k + 1];
            ai[k] = ge ? ai[2 * k] : ai[2 * k + 1];
        }
#pragma unroll
        for (int k = 0; k < 8; ++k) {
            const bool ge = av[2 * k] >= av[2 * k + 1];
            av[k] = ge ? av[2 * k] : av[2 * k + 1];
            ai[k] = ge ? ai[2 * k] : ai[2 * k + 1];
        }
#pragma unroll
        for (int k = 0; k < 4; ++k) {
            const bool ge = av[2 * k] >= av[2 * k + 1];
            av[k] = ge ? av[2 * k] : av[2 * k + 1];
            ai[k] = ge ? ai[2 * k] : ai[2 * k + 1];
        }
#pragma unroll
        for (int k = 0; k < 2; ++k) {
            const bool ge = av[2 * k] >= av[2 * k + 1];
            av[k] = ge ? av[2 * k] : av[2 * k + 1];
            ai[k] = ge ? ai[2 * k] : ai[2 * k + 1];
        }
        const bool ge = av[0] >= av[1];
        const int best = ge ? ai[0] : ai[1];

        hist[((size_t)b * (TT - 1) + pp) * NN + j] = (unsigned char)best;
    }
}

// ---------------------------------------------------------------------------
// Kernel 4: segmented-speculative backtrack. 16 segments x 64 candidate tags
// = 1024 threads; each walks its 64-step segment (dependent L2-hot byte
// reads) to build the segment's tag->tag map; thread 0 stitches the 16 maps;
// 16 walkers re-walk with the true entry tags and emit the path.
// ---------------------------------------------------------------------------
__global__ __launch_bounds__(1024) void viterbi_backtrack(
    const unsigned char* __restrict__ hist,   // [B, T-1, N]
    const int* __restrict__ last_arr,
    float* __restrict__ pred)
{
    __shared__ unsigned char mmap[16][64];
    __shared__ unsigned char in_tag[16];
    __shared__ unsigned char tagbuf[TT];

    const int b   = blockIdx.x;
    const int tid = threadIdx.x;
    const unsigned char* hb = hist + (size_t)b * (TT - 1) * NN;

    // phase 1: speculative segment maps
    const int s  = tid >> 6;
    const int x  = tid & 63;
    const int hi = (s == 15) ? (TT - 1) : (s * 64 + 63);
    const int lo = (s == 0) ? 1 : (s * 64);
    int cur = x;
    for (int t = hi; t >= lo; --t) cur = hb[(size_t)(t - 1) * NN + cur];
    mmap[s][x] = (unsigned char)cur;
    __syncthreads();

    // phase 2: stitch maps serially (16 steps)
    if (tid == 0) {
        int tag = last_arr[b];
        tagbuf[TT - 1] = (unsigned char)tag;
        for (int s2 = 15; s2 >= 0; --s2) {
            in_tag[s2] = (unsigned char)tag;   // tag at position hi_s
            tag = mmap[s2][tag];
        }
    }
    __syncthreads();

    // phase 3: 16 true re-walks in parallel; seg s writes positions
    // [lo-1, hi-1] (disjoint union = 0..1022)
    if (tid < 16) {
        const int s3  = tid;
        const int hi3 = (s3 == 15) ? (TT - 1) : (s3 * 64 + 63);
        const int lo3 = (s3 == 0) ? 1 : (s3 * 64);
        int c3 = in_tag[s3];
        for (int t = hi3; t >= lo3; --t) {
            c3 = hb[(size_t)(t - 1) * NN + c3];
            tagbuf[t - 1] = (unsigned char)c3;
        }
    }
    __syncthreads();

    float* pb = pred + (size_t)b * TT;
    for (int i = tid; i < TT; i += 1024) pb[i] = (float)tagbuf[i];
}

// ---------------------------------------------------------------------------
// Launch
// ---------------------------------------------------------------------------
extern "C" void kernel_launch(void* const* d_in, const int* in_sizes, int n_in,
                              void* d_out, int out_size, void* d_ws, size_t ws_size,
                              hipStream_t stream)
{
    const float* text_vec    = (const float*)d_in[0];
    // d_in[1] = mask (all true for this problem; unused)
    const float* W_em        = (const float*)d_in[2];
    const float* b_em        = (const float*)d_in[3];
    const float* start_trans = (const float*)d_in[4];
    const float* end_trans   = (const float*)d_in[5];
    const float* trans       = (const float*)d_in[6];

    float* emission = (float*)d_out;                        // [B*T*N]
    float* pred     = (float*)d_out + (size_t)BB * TT * NN; // [B*T]

    float* scores       = (float*)d_ws;                                    // 16.78 MB
    unsigned char* hist = (unsigned char*)d_ws + (size_t)BB * TT * NN * 4; // 4.19 MB
    int* last_arr       = (int*)(hist + (size_t)BB * (TT - 1) * NN);       // 256 B

    emission_gemm<<<dim3(512), dim3(256), 0, stream>>>(text_vec, W_em, b_em, emission);
    viterbi_forward<<<dim3(BB), dim3(64), 0, stream>>>(emission, start_trans, end_trans,
                                                       trans, scores, last_arr);
    viterbi_hist<<<dim3(16, BB), dim3(256), 0, stream>>>(scores, trans, hist);
    viterbi_backtrack<<<dim3(BB), dim3(1024), 0, stream>>>(hist, last_arr, pred);
}